// Round 7
// baseline (32.838 us; speedup 1.0000x reference)
//
#include <hip/hip_runtime.h>

// LIF forward: u_t = u + (ir_t - u)/10 ; o_t = 1[u_t >= 1] ; u_rest=0 -> no reset.
// R7: final knob — request depth. R4 (NT store, 31.1us) + unroll 20 (was 10):
// ~80 KB/CU loads in flight at 1 wave/SIMD (VGPRs free: occupancy is
// thread-count-bound). A/B: if flat vs R4, mixed-stream HBM efficiency is the
// wall -> roofline. Store A/B closed in R6: NT >= plain (31.1 vs 31.9).
// FETCH ~52MB structural (~half of ir MALL-resident; R5 proved not controllable).
// Exact IEEE f32 divide by 10.0f -> bitwise-identical to numpy ref (absmax 0.0).
// Spike test u >= 1.0f == (u-1)>=0 exactly (Sterbenz on [0.5,2]; sign-exact
// elsewhere).

#define T_STEPS 100
#define BN      262144        // B*N = 32*8192
#define VEC     4
#define NTHR    (BN / VEC)    // 65536 threads = 1024 waves = 1 wave/SIMD

typedef float f32x4 __attribute__((ext_vector_type(4)));

__global__ __launch_bounds__(256) void lif_fwd(const f32x4* __restrict__ ir,
                                               const f32x4* __restrict__ u0,
                                               f32x4* __restrict__ out) {
    const int idx = blockIdx.x * blockDim.x + threadIdx.x;   // 0..NTHR-1
    const int stride = BN / VEC;                             // f32x4 per time slab

    f32x4 u = u0[idx];

    #pragma unroll 20
    for (int t = 0; t < T_STEPS; ++t) {
        const f32x4 ir_t = ir[(size_t)t * stride + idx];

        // Bitwise-match reference: u + (-(u-0) + ir)/10 == u + (ir-u)/10.0f
        // (IEEE f32 division, no mul -> no FMA contraction hazard)
        f32x4 o;
        #pragma unroll
        for (int j = 0; j < VEC; ++j) {
            u[j] = u[j] + (ir_t[j] - u[j]) / 10.0f;
            o[j] = (u[j] >= 1.0f) ? 1.0f : 0.0f;
        }
        __builtin_nontemporal_store(o, &out[(size_t)t * stride + idx]);
        // u_next = u_t + u_rest * o_t = u_t  (u_rest == 0)
    }
}

extern "C" void kernel_launch(void* const* d_in, const int* in_sizes, int n_in,
                              void* d_out, int out_size, void* d_ws, size_t ws_size,
                              hipStream_t stream) {
    const f32x4* ir = (const f32x4*)d_in[0];   // [T, B, N] f32
    const f32x4* u0 = (const f32x4*)d_in[1];   // [B, N] f32
    f32x4* out = (f32x4*)d_out;                // [T, B, N] f32

    lif_fwd<<<dim3(NTHR / 256), dim3(256), 0, stream>>>(ir, u0, out);
}

// Round 8
// 31.044 us; speedup vs baseline: 1.0578x; 1.0578x over previous
//
#include <hip/hip_runtime.h>

// LIF forward: u_t = u + (ir_t - u)/10 ; o_t = 1[u_t >= 1] ; u_rest=0 -> no reset.
// FINAL (R4 config, best measured 31.1 us):
//   VEC=4 ext-vector (16 B/lane dwordx4 — the m13 6.3 TB/s pattern),
//   __builtin_nontemporal_store (A/B'd vs plain: 31.1 vs 31.9; vs sc1-nt asm: 52.2),
//   unroll 10 (~40 KB/CU loads in flight; unroll 20 A/B'd: 32.8 — flat/worse),
//   65536 threads = 1 wave/SIMD (width beats TLP: VEC=1/2/4 = 44.4/47.5/31.1 us).
// Roofline: 210 MB logical / 31.1 us = 6.75 TB/s fabric-served (> 6.3 TB/s copy
// ceiling; ~half of ir is MALL-resident). HBM-level 5.05 TB/s mixed R+W.
// Not compute (VALU ~3.7 us), not latency (depth A/B flat), not store path.
// Exact IEEE f32 divide by 10.0f -> bitwise-identical to numpy ref (absmax 0.0).
// Spike test u >= 1.0f == (u-1)>=0 exactly (Sterbenz on [0.5,2]; sign-exact
// elsewhere).

#define T_STEPS 100
#define BN      262144        // B*N = 32*8192
#define VEC     4
#define NTHR    (BN / VEC)    // 65536 threads

typedef float f32x4 __attribute__((ext_vector_type(4)));

__global__ __launch_bounds__(256) void lif_fwd(const f32x4* __restrict__ ir,
                                               const f32x4* __restrict__ u0,
                                               f32x4* __restrict__ out) {
    const int idx = blockIdx.x * blockDim.x + threadIdx.x;   // 0..NTHR-1
    const int stride = BN / VEC;                             // f32x4 per time slab

    f32x4 u = u0[idx];

    #pragma unroll 10
    for (int t = 0; t < T_STEPS; ++t) {
        const f32x4 ir_t = ir[(size_t)t * stride + idx];

        // Bitwise-match reference: u + (-(u-0) + ir)/10 == u + (ir-u)/10.0f
        // (IEEE f32 division, no mul -> no FMA contraction hazard)
        f32x4 o;
        #pragma unroll
        for (int j = 0; j < VEC; ++j) {
            u[j] = u[j] + (ir_t[j] - u[j]) / 10.0f;
            o[j] = (u[j] >= 1.0f) ? 1.0f : 0.0f;
        }
        __builtin_nontemporal_store(o, &out[(size_t)t * stride + idx]);
        // u_next = u_t + u_rest * o_t = u_t  (u_rest == 0)
    }
}

extern "C" void kernel_launch(void* const* d_in, const int* in_sizes, int n_in,
                              void* d_out, int out_size, void* d_ws, size_t ws_size,
                              hipStream_t stream) {
    const f32x4* ir = (const f32x4*)d_in[0];   // [T, B, N] f32
    const f32x4* u0 = (const f32x4*)d_in[1];   // [B, N] f32
    f32x4* out = (f32x4*)d_out;                // [T, B, N] f32

    lif_fwd<<<dim3(NTHR / 256), dim3(256), 0, stream>>>(ir, u0, out);
}